// Round 8
// baseline (240.840 us; speedup 1.0000x reference)
//
#include <hip/hip_runtime.h>
#include <hip/hip_bf16.h>
#include <hip/hip_fp16.h>
#include <math.h>

// Problem constants
#define NN 100000
#define EE 1600000
#define ET 1700000            // E + N self-loops
#define NEG_SLOPE 0.2f
#define XS_STRIDE 136         // 128 + 8 halves: kills LDS bank conflicts
#define L2E 1.44269504088896f

// bucket-sort CSR build (fixed slabs; no count/scan passes)
#define BKB 7                 // log2(dsts per bucket)
#define BKSZ 128
#define NBUCK 782             // ceil(NN / BKSZ)
#define SLAB 4096             // slots per bucket (mean ~2174 +pad ~2622, 31 sigma)
#define PAD 32                // ints per counter (one 128B line each)
#define EPT2 16
#define CHUNK2 (256 * EPT2)   // 4096 edges per block
#define NCH2 ((ET + CHUNK2 - 1) / CHUNK2)   // 416
#define GEMM_BLOCKS ((NN + 63) / 64)        // 1563

typedef _Float16 f16;
typedef f16 f16x4 __attribute__((ext_vector_type(4)));
typedef f16 f16x8 __attribute__((ext_vector_type(8)));
typedef float f32x4 __attribute__((ext_vector_type(4)));
typedef float f32x2 __attribute__((ext_vector_type(2)));

__device__ __forceinline__ float leaky(float v) {
    // slope in (0,1): leaky == max(v, slope*v) — 2 VALU, no branch
    return fmaxf(v, NEG_SLOPE * v);
}
__device__ __forceinline__ unsigned char enc_fp8(float v) {
    int pk = __builtin_amdgcn_cvt_pk_fp8_f32(v, 0.f, 0, false);
    return (unsigned char)(pk & 0xff);
}

// pair-fold: lanes with sb=0 keep X-sums, sb=1 keep Y-sums across offset off
__device__ __forceinline__ void fold8(float (&dst)[8], const float (&X)[8],
                                      const float (&Y)[8], int sb, int off) {
#pragma unroll
    for (int i = 0; i < 8; ++i) {
        float m = sb ? Y[i] : X[i];
        float o = sb ? X[i] : Y[i];
        dst[i] = m + __shfl_xor(o, off, 64);
    }
}

// node record: 128B per node = 8 heads x 16B chunk
//   chunk layout: [0:8) fp8 features (8 ch), [8:10) alpha_src half (pre *log2e),
//                 [10:12) pad, [12:16) alpha_dst float (pre *log2e)
// dummy record at node NN: fp8 = 0, alpha_src = -inf -> p = exp2(-inf) = 0

// ---------- B1: bucket fill; also folds in W1 transpose + dummy record ---
__global__ __launch_bounds__(256) void bucket_fill(
        const int* __restrict__ ei, int* __restrict__ bcur,
        unsigned* __restrict__ gpay, const float* __restrict__ W1,
        f16* __restrict__ wt, unsigned char* __restrict__ nrec) {
    const int tid = threadIdx.x;
    // merged convert_w: W1 fp32 [128][64] -> wt fp16 [64][128] (transposed)
    if (blockIdx.x < 32) {
        int i = blockIdx.x * 256 + tid;
        int n = i >> 7, k = i & 127;
        wt[n * 128 + k] = (f16)W1[k * 64 + n];
    }
    if (blockIdx.x == 32 && tid < 8) {
        uint4* dr = (uint4*)(nrec + (size_t)NN * 128);
        dr[tid] = make_uint4(0u, 0u, 0xFC00u, 0u);  // as1h = -inf
    }
    __shared__ int lcnt[NBUCK];
    __shared__ int gbase[NBUCK];
    for (int i = tid; i < NBUCK; i += 256) lcnt[i] = 0;
    __syncthreads();
    const int base = blockIdx.x * CHUNK2 + tid;
    unsigned pay[EPT2];
    int bk[EPT2], pos[EPT2];
#pragma unroll
    for (int k = 0; k < EPT2; ++k) {
        int e = base + k * 256;
        if (e < ET) {
            int s, d;
            if (e < EE) {
                s = __builtin_nontemporal_load(ei + e);
                d = __builtin_nontemporal_load(ei + EE + e);
            } else { s = d = e - EE; }
            int b = d >> BKB;
            bk[k] = b;
            pay[k] = ((unsigned)(d & (BKSZ - 1)) << 17) | (unsigned)s;
            pos[k] = atomicAdd(&lcnt[b], 1);
        } else bk[k] = -1;
    }
    __syncthreads();
    for (int i = tid; i < NBUCK; i += 256)
        gbase[i] = lcnt[i] ? (i * SLAB + atomicAdd(&bcur[i * PAD], lcnt[i])) : 0;
    __syncthreads();
#pragma unroll
    for (int k = 0; k < EPT2; ++k)
        if (bk[k] >= 0) gpay[gbase[bk[k]] + pos[k]] = pay[k];
}

// ---------- fused launch 2: fine_csr (blocks < NBUCK) + gemm1 (rest) -----
// Independent work (fine_csr needs bucket_fill; gemm1 needs convert_w —
// both complete after launch 1), co-scheduled in one grid so the
// LDS-atomic-bound CSR build overlaps the HBM/MFMA-bound GEMM.
__global__ __launch_bounds__(256) void gemm_csr_fused(
        // fine_csr args
        const unsigned* __restrict__ gpay, const int* __restrict__ bcur,
        int* __restrict__ rowptr, int* __restrict__ rowend,
        int* __restrict__ csr_src,
        // gemm1 args
        const float* __restrict__ x, const f16* __restrict__ wt,
        const float* __restrict__ att_s, const float* __restrict__ att_d,
        unsigned char* __restrict__ nrec) {
    __shared__ __align__(16) char smem[64 * XS_STRIDE * 2];   // 17408 B union
    const int tid = threadIdx.x;

    if (blockIdx.x < NBUCK) {
        // ================= fine_csr =================
        int* cnt = (int*)smem;          // BKSZ ints
        int* ts  = cnt + BKSZ;          // 256 ints
        const int b = blockIdx.x;
        const int off = b * SLAB;
        int blen = bcur[b * PAD];
        if (blen > SLAB) blen = SLAB;
        const int d0 = b << BKB;
        if (tid < BKSZ) cnt[tid] = 0;
        __syncthreads();
        for (int i = tid; i < blen; i += 256)
            atomicAdd(&cnt[gpay[off + i] >> 17], 1);
        __syncthreads();
        int v = (tid < BKSZ) ? cnt[tid] : 0;
        int vp = (v + 7) & ~7;        // padded row length (multiple of 8)
        ts[tid] = vp;
        __syncthreads();
        for (int o = 1; o < 256; o <<= 1) {
            int u = (tid >= o) ? ts[tid - o] : 0;
            __syncthreads();
            ts[tid] += u;
            __syncthreads();
        }
        int excl = ts[tid] - vp;
        if (excl + vp > SLAB) vp = v;  // pathological-overflow guard
        if (tid < BKSZ) cnt[tid] = excl;  // cursor = exclusive padded offset
        int d = d0 + tid;
        if (tid < BKSZ && d < NN) {
            rowptr[d] = off + excl;
            rowend[d] = off + excl + v;   // TRUE end (conv2 uses this)
        }
        for (int i = v; i < vp; ++i) csr_src[off + excl + i] = NN;
        __syncthreads();
        for (int i = tid; i < blen; i += 256) {
            unsigned pay = gpay[off + i];
            int pos = atomicAdd(&cnt[pay >> 17], 1);
            csr_src[off + pos] = (int)(pay & 0x1FFFFu);
        }
        return;
    }

    // ================= gemm1 =================
    f16* xs = (f16*)smem;
    const int node0 = (blockIdx.x - NBUCK) * 64;
    for (int i = tid; i < 64 * 32; i += 256) {
        int r = i >> 5, cp = i & 31;
        int n = node0 + r;
        float4 v = (n < NN) ? ((const float4*)x)[(long)n * 32 + cp]
                            : make_float4(0.f, 0.f, 0.f, 0.f);
        f16x4 h = {(f16)v.x, (f16)v.y, (f16)v.z, (f16)v.w};
        *(f16x4*)(xs + r * XS_STRIDE + 4 * cp) = h;
    }
    __syncthreads();
    const int wv = tid >> 6;
    const int lane = tid & 63;
    const int n16 = lane & 15;
    const int quad = lane >> 4;
    f16x8 bf[4][4];
#pragma unroll
    for (int t = 0; t < 4; ++t)
#pragma unroll
        for (int kk = 0; kk < 4; ++kk)
            bf[t][kk] = *(const f16x8*)(wt + ((t * 16 + n16) * 128 + kk * 32 + quad * 8));
    f32x4 acc[4] = {{0,0,0,0},{0,0,0,0},{0,0,0,0},{0,0,0,0}};
#pragma unroll
    for (int kk = 0; kk < 4; ++kk) {
        f16x8 af = *(const f16x8*)(xs + ((wv * 16 + n16) * XS_STRIDE + kk * 32 + quad * 8));
#pragma unroll
        for (int t = 0; t < 4; ++t)
            acc[t] = __builtin_amdgcn_mfma_f32_16x16x32_f16(af, bf[t][kk], acc[t], 0, 0, 0);
    }
    float ats[4], atd[4];
#pragma unroll
    for (int t = 0; t < 4; ++t) {
        ats[t] = att_s[t * 16 + n16];
        atd[t] = att_d[t * 16 + n16];
    }
    const int head = (n16 >> 3);            // + t*2
    const int chpos = n16 & 7;
#pragma unroll
    for (int t = 0; t < 4; ++t)
#pragma unroll
        for (int r = 0; r < 4; ++r) {
            int m = node0 + wv * 16 + quad * 4 + r;
            bool ok = (m < NN);
            if (ok)
                nrec[(size_t)m * 128 + (t * 2 + head) * 16 + chpos] =
                    enc_fp8(acc[t][r]);
            float vs = acc[t][r] * ats[t];
            float vd = acc[t][r] * atd[t];
            vs += __shfl_xor(vs, 1, 64); vd += __shfl_xor(vd, 1, 64);
            vs += __shfl_xor(vs, 2, 64); vd += __shfl_xor(vd, 2, 64);
            vs += __shfl_xor(vs, 4, 64); vd += __shfl_xor(vd, 4, 64);
            if (ok && chpos == 0) {
                unsigned char* nb = nrec + (size_t)m * 128 + (t * 2 + head) * 16;
                *(__half*)(nb + 8)  = __float2half_rn(vs * L2E);
                *(float*)(nb + 12) = vd * L2E;
            }
        }
}

// ---------- conv1 fused: 4 nodes per wave, unified masked loop -----------
__global__ __launch_bounds__(256) void conv1_fused_kernel(
        const int* __restrict__ rowptr, const int* __restrict__ rowend,
        const int* __restrict__ csr_src, const unsigned char* __restrict__ nrec,
        const float* __restrict__ b1, const float* __restrict__ W2,
        const float* __restrict__ as2, const float* __restrict__ ad2,
        float4* __restrict__ rec) {
    const int tid = threadIdx.x;
    const int wv = tid >> 6;
    const int c = tid & 63;
    const int slot = c >> 3;      // edge slot within an 8-edge group
    const int hd = c & 7;         // head; lane owns channels hd*8..hd*8+7
    const int sb0 = slot & 1, sb1 = (slot >> 1) & 1, sb2 = (slot >> 2) & 1;
    int n0 = __builtin_amdgcn_readfirstlane((blockIdx.x * 4 + wv) * 4);
    // nodes n0..n0+3; grid*4*4 == NN exactly
    const float adA = *(const float*)(nrec + ((size_t)(n0 + 0) << 7) + (hd << 4) + 12);
    const float adB = *(const float*)(nrec + ((size_t)(n0 + 1) << 7) + (hd << 4) + 12);
    const float adC = *(const float*)(nrec + ((size_t)(n0 + 2) << 7) + (hd << 4) + 12);
    const float adD = *(const float*)(nrec + ((size_t)(n0 + 3) << 7) + (hd << 4) + 12);
    int jA = rowptr[n0 + 0], eA = jA + ((rowend[n0 + 0] - jA + 7) & ~7);
    int jB = rowptr[n0 + 1], eB = jB + ((rowend[n0 + 1] - jB + 7) & ~7);
    int jC = rowptr[n0 + 2], eC = jC + ((rowend[n0 + 2] - jC + 7) & ~7);
    int jD = rowptr[n0 + 3], eD = jD + ((rowend[n0 + 3] - jD + 7) & ~7);
    float accA[8] = {0,0,0,0,0,0,0,0}, accB[8] = {0,0,0,0,0,0,0,0};
    float accC[8] = {0,0,0,0,0,0,0,0}, accD[8] = {0,0,0,0,0,0,0,0};
    float lA = 0.f, lB = 0.f, lC = 0.f, lD = 0.f;

#define STEP(j, e, ad, l, acc)                                               \
    {                                                                        \
        int jj = (j) < (e) - 8 ? (j) : (e) - 8;   /* clamp: rows >= 8 */     \
        int src = csr_src[jj + slot];                                        \
        uint4 v = *(const uint4*)(nrec + (((size_t)src << 7) | (hd << 4)));  \
        unsigned short ush = (unsigned short)v.z;                            \
        float as = __half2float(*(const __half*)&ush);                       \
        float p = exp2f(leaky(as + (ad)));                                   \
        p = ((j) < (e)) ? p : 0.f;                                           \
        f32x2 f01 = __builtin_amdgcn_cvt_pk_f32_fp8((int)v.x, 0);            \
        f32x2 f23 = __builtin_amdgcn_cvt_pk_f32_fp8((int)v.x, 1);            \
        f32x2 f45 = __builtin_amdgcn_cvt_pk_f32_fp8((int)v.y, 0);            \
        f32x2 f67 = __builtin_amdgcn_cvt_pk_f32_fp8((int)v.y, 1);            \
        (l) += p;                                                            \
        acc[0] += p * f01.x; acc[1] += p * f01.y;                            \
        acc[2] += p * f23.x; acc[3] += p * f23.y;                            \
        acc[4] += p * f45.x; acc[5] += p * f45.y;                            \
        acc[6] += p * f67.x; acc[7] += p * f67.y;                            \
        (j) += 8;                                                            \
    }

    while (jA < eA || jB < eB || jC < eC || jD < eD) {
        STEP(jA, eA, adA, lA, accA);
        STEP(jB, eB, adB, lB, accB);
        STEP(jC, eC, adC, lC, accC);
        STEP(jD, eD, adD, lD, accD);
    }
#undef STEP

    // ---- pair-fold butterfly ----
    float P[8], Q[8];
    fold8(P, accA, accB, sb0, 8);
    fold8(Q, accC, accD, sb0, 8);
    float lP, lQ, lm, lo;
    lm = sb0 ? lB : lA; lo = sb0 ? lA : lB;
    lP = lm + __shfl_xor(lo, 8, 64);
    lm = sb0 ? lD : lC; lo = sb0 ? lC : lD;
    lQ = lm + __shfl_xor(lo, 8, 64);
    float R[8];
    fold8(R, P, Q, sb1, 16);
    lm = sb1 ? lQ : lP; lo = sb1 ? lP : lQ;
    float l = lm + __shfl_xor(lo, 16, 64);
    float S[4];
#pragma unroll
    for (int i = 0; i < 4; ++i) {
        float m = sb2 ? R[i + 4] : R[i];
        float o = sb2 ? R[i] : R[i + 4];
        S[i] = m + __shfl_xor(o, 32, 64);
    }
    l += __shfl_xor(l, 32, 64);
    const int cb = (hd << 3) + sb2 * 4;
    float inv = 1.f / (l + 1e-16f);
    float4 bb = *(const float4*)(b1 + cb);
    float4 w01 = *(const float4*)(W2 + cb * 2);
    float4 w23 = *(const float4*)(W2 + cb * 2 + 4);
    float v0 = fmaxf(S[0] * inv + bb.x, 0.f);
    float v1 = fmaxf(S[1] * inv + bb.y, 0.f);
    float v2 = fmaxf(S[2] * inv + bb.z, 0.f);
    float v3 = fmaxf(S[3] * inv + bb.w, 0.f);
    float r0 = v0 * w01.x + v1 * w01.z + v2 * w23.x + v3 * w23.z;
    float r1 = v0 * w01.y + v1 * w01.w + v2 * w23.y + v3 * w23.w;
    r0 += __shfl_xor(r0, 1, 64);  r1 += __shfl_xor(r1, 1, 64);
    r0 += __shfl_xor(r0, 2, 64);  r1 += __shfl_xor(r1, 2, 64);
    r0 += __shfl_xor(r0, 4, 64);  r1 += __shfl_xor(r1, 4, 64);
    r0 += __shfl_xor(r0, 32, 64); r1 += __shfl_xor(r1, 32, 64);
    if (hd == 0 && sb2 == 0) {
        int n = n0 + sb1 * 2 + sb0;
        rec[n] = make_float4((r0 * as2[0] + r1 * as2[1]) * L2E, r0, r1,
                             (r0 * ad2[0] + r1 * ad2[1]) * L2E);
    }
}

// ---------- conv2 + mean-pool: 2 lanes per node (halved serial chain) ----
__global__ __launch_bounds__(256) void conv2_pool_kernel(
        const int* __restrict__ rowptr, const int* __restrict__ rowend,
        const int* __restrict__ csr_src, const float4* __restrict__ rec,
        const int* __restrict__ batch,
        float* __restrict__ pooled /*128 sums + 64 counts*/) {
    __shared__ float ls[192];
    int tid = threadIdx.x;
    if (tid < 192) ls[tid] = 0.f;
    __syncthreads();
    int q = tid & 1;
    int n = blockIdx.x * 128 + (tid >> 1);
    if (n < NN) {
        float adn = rec[n].w;
        int jb = rowptr[n], je = rowend[n];
        float l0 = 0.f, l1 = 0.f;
        float x0 = 0.f, x1 = 0.f;
        float y0 = 0.f, y1 = 0.f;
        int j = jb + q;
        for (; j + 2 < je; j += 4) {        // this lane: j and j+2
            float4 ra = rec[csr_src[j]];
            float4 rb = rec[csr_src[j + 2]];
            float pa = exp2f(leaky(ra.x + adn));
            float pb = exp2f(leaky(rb.x + adn));
            l0 += pa; x0 += pa * ra.y; y0 += pa * ra.z;
            l1 += pb; x1 += pb * rb.y; y1 += pb * rb.z;
        }
        if (j < je) {
            float4 ra = rec[csr_src[j]];
            float pa = exp2f(leaky(ra.x + adn));
            l0 += pa; x0 += pa * ra.y; y0 += pa * ra.z;
        }
        float l = l0 + l1, xx = x0 + x1, yy = y0 + y1;
        l += __shfl_xor(l, 1, 64);
        xx += __shfl_xor(xx, 1, 64);
        yy += __shfl_xor(yy, 1, 64);
        if (q == 0) {
            float inv = 1.f / (l + 1e-16f);
            int g = batch[n];
            atomicAdd(&ls[g * 2],     xx * inv);
            atomicAdd(&ls[g * 2 + 1], yy * inv);
            atomicAdd(&ls[128 + g],   1.f);
        }
    }
    __syncthreads();
    if (tid < 192) atomicAdd(&pooled[tid], ls[tid]);
}

// ---------- finalize: mean, +b2, log_softmax ----------
__global__ __launch_bounds__(64) void final_kernel(
        const float* __restrict__ pooled, const float* __restrict__ b2,
        float* __restrict__ out) {
    int g = threadIdx.x;
    if (g >= 64) return;
    float c = pooled[128 + g];
    float denom = c > 1.f ? c : 1.f;
    float p0 = pooled[g * 2] / denom + b2[0];
    float p1 = pooled[g * 2 + 1] / denom + b2[1];
    float m = fmaxf(p0, p1);
    float lse = m + logf(expf(p0 - m) + expf(p1 - m));
    out[g * 2] = p0 - lse;
    out[g * 2 + 1] = p1 - lse;
}

extern "C" void kernel_launch(void* const* d_in, const int* in_sizes, int n_in,
                              void* d_out, int out_size, void* d_ws, size_t ws_size,
                              hipStream_t stream) {
    const float* x   = (const float*)d_in[0];
    const int*   ei  = (const int*)d_in[1];     // [2,E] int32
    const int*   bat = (const int*)d_in[2];     // [N]
    const float* W1  = (const float*)d_in[3];
    const float* as1 = (const float*)d_in[4];
    const float* ad1 = (const float*)d_in[5];
    const float* b1  = (const float*)d_in[6];
    const float* W2  = (const float*)d_in[7];
    const float* as2 = (const float*)d_in[8];
    const float* ad2 = (const float*)d_in[9];
    const float* b2  = (const float*)d_in[10];
    float* out = (float*)d_out;

    float* ws = (float*)d_ws;
    // workspace layout (element offsets; 16B-aligned blocks)
    const long off_nrec   = 0;                               // (NN+1)*128B
    const long off_wt     = off_nrec + (long)(NN + 1) * 32;  // 8192 halves
    const long off_rec    = off_wt + 4096;                   // NN*4 (float4)
    const long off_rowptr = off_rec + (long)NN * 4;          // N (int)
    const long off_rowend = off_rowptr + NN;                 // N (int)
    const long off_gpay   = off_rowend + NN;                 // NBUCK*SLAB (uint)
    const long off_csr    = off_gpay + (long)NBUCK * SLAB;   // NBUCK*SLAB (int)
    const long off_zero   = off_csr + (long)NBUCK * SLAB;    // ---- zeroed ----
    const long off_bcur   = off_zero;                        // NBUCK*PAD (int)
    const long off_pool   = off_bcur + (long)NBUCK * PAD;    // 192
    const long zero_elems = off_pool + 192 - off_zero;

    hipMemsetAsync(ws + off_zero, 0, zero_elems * sizeof(float), stream);

    bucket_fill<<<NCH2, 256, 0, stream>>>(
        ei, (int*)(ws + off_bcur), (unsigned*)(ws + off_gpay),
        W1, (f16*)(ws + off_wt), (unsigned char*)(ws + off_nrec));

    gemm_csr_fused<<<NBUCK + GEMM_BLOCKS, 256, 0, stream>>>(
        (const unsigned*)(ws + off_gpay), (const int*)(ws + off_bcur),
        (int*)(ws + off_rowptr), (int*)(ws + off_rowend),
        (int*)(ws + off_csr),
        x, (const f16*)(ws + off_wt), as1, ad1,
        (unsigned char*)(ws + off_nrec));

    conv1_fused_kernel<<<NN / 16, 256, 0, stream>>>(
        (const int*)(ws + off_rowptr), (const int*)(ws + off_rowend),
        (const int*)(ws + off_csr), (const unsigned char*)(ws + off_nrec),
        b1, W2, as2, ad2, (float4*)(ws + off_rec));

    conv2_pool_kernel<<<(NN + 127) / 128, 256, 0, stream>>>(
        (const int*)(ws + off_rowptr), (const int*)(ws + off_rowend),
        (const int*)(ws + off_csr), (const float4*)(ws + off_rec),
        bat, ws + off_pool);

    final_kernel<<<1, 64, 0, stream>>>(ws + off_pool, b2, out);
}

// Round 9
// 234.048 us; speedup vs baseline: 1.0290x; 1.0290x over previous
//
#include <hip/hip_runtime.h>
#include <hip/hip_bf16.h>
#include <hip/hip_fp16.h>
#include <math.h>

// Problem constants
#define NN 100000
#define EE 1600000
#define ET 1700000            // E + N self-loops
#define NEG_SLOPE 0.2f
#define XS_STRIDE 136         // 128 + 8 halves: kills LDS bank conflicts
#define L2E 1.44269504088896f

// bucket-sort CSR build (fixed slabs; no count/scan passes)
#define BKB 7                 // log2(dsts per bucket)
#define BKSZ 128
#define NBUCK 782             // ceil(NN / BKSZ)
#define SLAB 4096             // slots per bucket (mean ~2174 +pad ~2622, 31 sigma)
#define PAD 32                // ints per counter (one 128B line each)
#define EPT2 4                // edges per thread (1024-thread blocks)
#define CHUNK2 (1024 * EPT2)  // 4096 edges per block
#define NCH2 ((ET + CHUNK2 - 1) / CHUNK2)   // 416
#define GEMM_BLOCKS ((NN + 63) / 64)        // 1563

typedef _Float16 f16;
typedef f16 f16x4 __attribute__((ext_vector_type(4)));
typedef f16 f16x8 __attribute__((ext_vector_type(8)));
typedef float f32x4 __attribute__((ext_vector_type(4)));
typedef float f32x2 __attribute__((ext_vector_type(2)));

__device__ __forceinline__ float leaky(float v) {
    // slope in (0,1): leaky == max(v, slope*v) — 2 VALU, no branch
    return fmaxf(v, NEG_SLOPE * v);
}
__device__ __forceinline__ unsigned char enc_fp8(float v) {
    int pk = __builtin_amdgcn_cvt_pk_fp8_f32(v, 0.f, 0, false);
    return (unsigned char)(pk & 0xff);
}

// pair-fold: lanes with sb=0 keep X-sums, sb=1 keep Y-sums across offset off
__device__ __forceinline__ void fold8(float (&dst)[8], const float (&X)[8],
                                      const float (&Y)[8], int sb, int off) {
#pragma unroll
    for (int i = 0; i < 8; ++i) {
        float m = sb ? Y[i] : X[i];
        float o = sb ? X[i] : Y[i];
        dst[i] = m + __shfl_xor(o, off, 64);
    }
}

// node record: 128B per node = 8 heads x 16B chunk
//   chunk layout: [0:8) fp8 features (8 ch), [8:10) alpha_src half (pre *log2e),
//                 [10:12) pad, [12:16) alpha_dst float (pre *log2e)
// dummy record at node NN: fp8 = 0, alpha_src = -inf -> p = exp2(-inf) = 0

// ---------- B1: bucket fill (1024 thr, 4 edges/thr: 4x occupancy) --------
// Same 4096-edge chunk per block as before (preserves contiguous per-bucket
// slot runs -> write coalescing), but 16 waves/block instead of 4: the
// latency-bound {load -> LDS atomic -> scatter} chain now has 26 waves/CU
// to hide under instead of 6.5 (R8 profile: occupancy 12.6%, VALU 1.9%).
__global__ __launch_bounds__(1024) void bucket_fill(
        const int* __restrict__ ei, int* __restrict__ bcur,
        unsigned* __restrict__ gpay, const float* __restrict__ W1,
        f16* __restrict__ wt, unsigned char* __restrict__ nrec) {
    const int tid = threadIdx.x;
    // merged convert_w: W1 fp32 [128][64] -> wt fp16 [64][128] (transposed)
    if (blockIdx.x < 8) {
        int i = blockIdx.x * 1024 + tid;     // 8*1024 == 128*64
        int n = i >> 7, k = i & 127;
        wt[n * 128 + k] = (f16)W1[k * 64 + n];
    }
    if (blockIdx.x == 8 && tid < 8) {
        uint4* dr = (uint4*)(nrec + (size_t)NN * 128);
        dr[tid] = make_uint4(0u, 0u, 0xFC00u, 0u);  // as1h = -inf
    }
    __shared__ int lcnt[NBUCK];
    __shared__ int gbase[NBUCK];
    for (int i = tid; i < NBUCK; i += 1024) lcnt[i] = 0;
    __syncthreads();
    const int base = blockIdx.x * CHUNK2 + tid;
    unsigned pay[EPT2];
    int bk[EPT2], pos[EPT2];
#pragma unroll
    for (int k = 0; k < EPT2; ++k) {
        int e = base + k * 1024;
        if (e < ET) {
            int s, d;
            if (e < EE) {
                s = __builtin_nontemporal_load(ei + e);
                d = __builtin_nontemporal_load(ei + EE + e);
            } else { s = d = e - EE; }
            int b = d >> BKB;
            bk[k] = b;
            pay[k] = ((unsigned)(d & (BKSZ - 1)) << 17) | (unsigned)s;
            pos[k] = atomicAdd(&lcnt[b], 1);
        } else bk[k] = -1;
    }
    __syncthreads();
    for (int i = tid; i < NBUCK; i += 1024)
        gbase[i] = lcnt[i] ? (i * SLAB + atomicAdd(&bcur[i * PAD], lcnt[i])) : 0;
    __syncthreads();
#pragma unroll
    for (int k = 0; k < EPT2; ++k)
        if (bk[k] >= 0) gpay[gbase[bk[k]] + pos[k]] = pay[k];
}

// ---------- fused launch 2: fine_csr (blocks < NBUCK) + gemm1 (rest) -----
// Independent work (fine_csr needs bucket_fill; gemm1 needs convert_w —
// both complete after launch 1), co-scheduled in one grid so the
// LDS-atomic-bound CSR build overlaps the HBM/MFMA-bound GEMM.
__global__ __launch_bounds__(256) void gemm_csr_fused(
        // fine_csr args
        const unsigned* __restrict__ gpay, const int* __restrict__ bcur,
        int* __restrict__ rowptr, int* __restrict__ rowend,
        int* __restrict__ csr_src,
        // gemm1 args
        const float* __restrict__ x, const f16* __restrict__ wt,
        const float* __restrict__ att_s, const float* __restrict__ att_d,
        unsigned char* __restrict__ nrec) {
    __shared__ __align__(16) char smem[64 * XS_STRIDE * 2];   // 17408 B union
    const int tid = threadIdx.x;

    if (blockIdx.x < NBUCK) {
        // ================= fine_csr =================
        int* cnt = (int*)smem;          // BKSZ ints
        int* ts  = cnt + BKSZ;          // 256 ints
        const int b = blockIdx.x;
        const int off = b * SLAB;
        int blen = bcur[b * PAD];
        if (blen > SLAB) blen = SLAB;
        const int d0 = b << BKB;
        if (tid < BKSZ) cnt[tid] = 0;
        __syncthreads();
        for (int i = tid; i < blen; i += 256)
            atomicAdd(&cnt[gpay[off + i] >> 17], 1);
        __syncthreads();
        int v = (tid < BKSZ) ? cnt[tid] : 0;
        int vp = (v + 7) & ~7;        // padded row length (multiple of 8)
        ts[tid] = vp;
        __syncthreads();
        for (int o = 1; o < 256; o <<= 1) {
            int u = (tid >= o) ? ts[tid - o] : 0;
            __syncthreads();
            ts[tid] += u;
            __syncthreads();
        }
        int excl = ts[tid] - vp;
        if (excl + vp > SLAB) vp = v;  // pathological-overflow guard
        if (tid < BKSZ) cnt[tid] = excl;  // cursor = exclusive padded offset
        int d = d0 + tid;
        if (tid < BKSZ && d < NN) {
            rowptr[d] = off + excl;
            rowend[d] = off + excl + v;   // TRUE end (conv2 uses this)
        }
        for (int i = v; i < vp; ++i) csr_src[off + excl + i] = NN;
        __syncthreads();
        for (int i = tid; i < blen; i += 256) {
            unsigned pay = gpay[off + i];
            int pos = atomicAdd(&cnt[pay >> 17], 1);
            csr_src[off + pos] = (int)(pay & 0x1FFFFu);
        }
        return;
    }

    // ================= gemm1 =================
    f16* xs = (f16*)smem;
    const int node0 = (blockIdx.x - NBUCK) * 64;
    for (int i = tid; i < 64 * 32; i += 256) {
        int r = i >> 5, cp = i & 31;
        int n = node0 + r;
        float4 v = (n < NN) ? ((const float4*)x)[(long)n * 32 + cp]
                            : make_float4(0.f, 0.f, 0.f, 0.f);
        f16x4 h = {(f16)v.x, (f16)v.y, (f16)v.z, (f16)v.w};
        *(f16x4*)(xs + r * XS_STRIDE + 4 * cp) = h;
    }
    __syncthreads();
    const int wv = tid >> 6;
    const int lane = tid & 63;
    const int n16 = lane & 15;
    const int quad = lane >> 4;
    f16x8 bf[4][4];
#pragma unroll
    for (int t = 0; t < 4; ++t)
#pragma unroll
        for (int kk = 0; kk < 4; ++kk)
            bf[t][kk] = *(const f16x8*)(wt + ((t * 16 + n16) * 128 + kk * 32 + quad * 8));
    f32x4 acc[4] = {{0,0,0,0},{0,0,0,0},{0,0,0,0},{0,0,0,0}};
#pragma unroll
    for (int kk = 0; kk < 4; ++kk) {
        f16x8 af = *(const f16x8*)(xs + ((wv * 16 + n16) * XS_STRIDE + kk * 32 + quad * 8));
#pragma unroll
        for (int t = 0; t < 4; ++t)
            acc[t] = __builtin_amdgcn_mfma_f32_16x16x32_f16(af, bf[t][kk], acc[t], 0, 0, 0);
    }
    float ats[4], atd[4];
#pragma unroll
    for (int t = 0; t < 4; ++t) {
        ats[t] = att_s[t * 16 + n16];
        atd[t] = att_d[t * 16 + n16];
    }
    const int head = (n16 >> 3);            // + t*2
    const int chpos = n16 & 7;
#pragma unroll
    for (int t = 0; t < 4; ++t)
#pragma unroll
        for (int r = 0; r < 4; ++r) {
            int m = node0 + wv * 16 + quad * 4 + r;
            bool ok = (m < NN);
            if (ok)
                nrec[(size_t)m * 128 + (t * 2 + head) * 16 + chpos] =
                    enc_fp8(acc[t][r]);
            float vs = acc[t][r] * ats[t];
            float vd = acc[t][r] * atd[t];
            vs += __shfl_xor(vs, 1, 64); vd += __shfl_xor(vd, 1, 64);
            vs += __shfl_xor(vs, 2, 64); vd += __shfl_xor(vd, 2, 64);
            vs += __shfl_xor(vs, 4, 64); vd += __shfl_xor(vd, 4, 64);
            if (ok && chpos == 0) {
                unsigned char* nb = nrec + (size_t)m * 128 + (t * 2 + head) * 16;
                *(__half*)(nb + 8)  = __float2half_rn(vs * L2E);
                *(float*)(nb + 12) = vd * L2E;
            }
        }
}

// ---------- conv1 fused: 4 nodes per wave, unified masked loop -----------
__global__ __launch_bounds__(256) void conv1_fused_kernel(
        const int* __restrict__ rowptr, const int* __restrict__ rowend,
        const int* __restrict__ csr_src, const unsigned char* __restrict__ nrec,
        const float* __restrict__ b1, const float* __restrict__ W2,
        const float* __restrict__ as2, const float* __restrict__ ad2,
        float4* __restrict__ rec) {
    const int tid = threadIdx.x;
    const int wv = tid >> 6;
    const int c = tid & 63;
    const int slot = c >> 3;      // edge slot within an 8-edge group
    const int hd = c & 7;         // head; lane owns channels hd*8..hd*8+7
    const int sb0 = slot & 1, sb1 = (slot >> 1) & 1, sb2 = (slot >> 2) & 1;
    int n0 = __builtin_amdgcn_readfirstlane((blockIdx.x * 4 + wv) * 4);
    // nodes n0..n0+3; grid*4*4 == NN exactly
    const float adA = *(const float*)(nrec + ((size_t)(n0 + 0) << 7) + (hd << 4) + 12);
    const float adB = *(const float*)(nrec + ((size_t)(n0 + 1) << 7) + (hd << 4) + 12);
    const float adC = *(const float*)(nrec + ((size_t)(n0 + 2) << 7) + (hd << 4) + 12);
    const float adD = *(const float*)(nrec + ((size_t)(n0 + 3) << 7) + (hd << 4) + 12);
    int jA = rowptr[n0 + 0], eA = jA + ((rowend[n0 + 0] - jA + 7) & ~7);
    int jB = rowptr[n0 + 1], eB = jB + ((rowend[n0 + 1] - jB + 7) & ~7);
    int jC = rowptr[n0 + 2], eC = jC + ((rowend[n0 + 2] - jC + 7) & ~7);
    int jD = rowptr[n0 + 3], eD = jD + ((rowend[n0 + 3] - jD + 7) & ~7);
    float accA[8] = {0,0,0,0,0,0,0,0}, accB[8] = {0,0,0,0,0,0,0,0};
    float accC[8] = {0,0,0,0,0,0,0,0}, accD[8] = {0,0,0,0,0,0,0,0};
    float lA = 0.f, lB = 0.f, lC = 0.f, lD = 0.f;

#define STEP(j, e, ad, l, acc)                                               \
    {                                                                        \
        int jj = (j) < (e) - 8 ? (j) : (e) - 8;   /* clamp: rows >= 8 */     \
        int src = csr_src[jj + slot];                                        \
        uint4 v = *(const uint4*)(nrec + (((size_t)src << 7) | (hd << 4)));  \
        unsigned short ush = (unsigned short)v.z;                            \
        float as = __half2float(*(const __half*)&ush);                       \
        float p = exp2f(leaky(as + (ad)));                                   \
        p = ((j) < (e)) ? p : 0.f;                                           \
        f32x2 f01 = __builtin_amdgcn_cvt_pk_f32_fp8((int)v.x, 0);            \
        f32x2 f23 = __builtin_amdgcn_cvt_pk_f32_fp8((int)v.x, 1);            \
        f32x2 f45 = __builtin_amdgcn_cvt_pk_f32_fp8((int)v.y, 0);            \
        f32x2 f67 = __builtin_amdgcn_cvt_pk_f32_fp8((int)v.y, 1);            \
        (l) += p;                                                            \
        acc[0] += p * f01.x; acc[1] += p * f01.y;                            \
        acc[2] += p * f23.x; acc[3] += p * f23.y;                            \
        acc[4] += p * f45.x; acc[5] += p * f45.y;                            \
        acc[6] += p * f67.x; acc[7] += p * f67.y;                            \
        (j) += 8;                                                            \
    }

    while (jA < eA || jB < eB || jC < eC || jD < eD) {
        STEP(jA, eA, adA, lA, accA);
        STEP(jB, eB, adB, lB, accB);
        STEP(jC, eC, adC, lC, accC);
        STEP(jD, eD, adD, lD, accD);
    }
#undef STEP

    // ---- pair-fold butterfly ----
    float P[8], Q[8];
    fold8(P, accA, accB, sb0, 8);
    fold8(Q, accC, accD, sb0, 8);
    float lP, lQ, lm, lo;
    lm = sb0 ? lB : lA; lo = sb0 ? lA : lB;
    lP = lm + __shfl_xor(lo, 8, 64);
    lm = sb0 ? lD : lC; lo = sb0 ? lC : lD;
    lQ = lm + __shfl_xor(lo, 8, 64);
    float R[8];
    fold8(R, P, Q, sb1, 16);
    lm = sb1 ? lQ : lP; lo = sb1 ? lP : lQ;
    float l = lm + __shfl_xor(lo, 16, 64);
    float S[4];
#pragma unroll
    for (int i = 0; i < 4; ++i) {
        float m = sb2 ? R[i + 4] : R[i];
        float o = sb2 ? R[i] : R[i + 4];
        S[i] = m + __shfl_xor(o, 32, 64);
    }
    l += __shfl_xor(l, 32, 64);
    const int cb = (hd << 3) + sb2 * 4;
    float inv = 1.f / (l + 1e-16f);
    float4 bb = *(const float4*)(b1 + cb);
    float4 w01 = *(const float4*)(W2 + cb * 2);
    float4 w23 = *(const float4*)(W2 + cb * 2 + 4);
    float v0 = fmaxf(S[0] * inv + bb.x, 0.f);
    float v1 = fmaxf(S[1] * inv + bb.y, 0.f);
    float v2 = fmaxf(S[2] * inv + bb.z, 0.f);
    float v3 = fmaxf(S[3] * inv + bb.w, 0.f);
    float r0 = v0 * w01.x + v1 * w01.z + v2 * w23.x + v3 * w23.z;
    float r1 = v0 * w01.y + v1 * w01.w + v2 * w23.y + v3 * w23.w;
    r0 += __shfl_xor(r0, 1, 64);  r1 += __shfl_xor(r1, 1, 64);
    r0 += __shfl_xor(r0, 2, 64);  r1 += __shfl_xor(r1, 2, 64);
    r0 += __shfl_xor(r0, 4, 64);  r1 += __shfl_xor(r1, 4, 64);
    r0 += __shfl_xor(r0, 32, 64); r1 += __shfl_xor(r1, 32, 64);
    if (hd == 0 && sb2 == 0) {
        int n = n0 + sb1 * 2 + sb0;
        rec[n] = make_float4((r0 * as2[0] + r1 * as2[1]) * L2E, r0, r1,
                             (r0 * ad2[0] + r1 * ad2[1]) * L2E);
    }
}

// ---------- conv2 + mean-pool: 2 lanes per node (halved serial chain) ----
__global__ __launch_bounds__(256) void conv2_pool_kernel(
        const int* __restrict__ rowptr, const int* __restrict__ rowend,
        const int* __restrict__ csr_src, const float4* __restrict__ rec,
        const int* __restrict__ batch,
        float* __restrict__ pooled /*128 sums + 64 counts*/) {
    __shared__ float ls[192];
    int tid = threadIdx.x;
    if (tid < 192) ls[tid] = 0.f;
    __syncthreads();
    int q = tid & 1;
    int n = blockIdx.x * 128 + (tid >> 1);
    if (n < NN) {
        float adn = rec[n].w;
        int jb = rowptr[n], je = rowend[n];
        float l0 = 0.f, l1 = 0.f;
        float x0 = 0.f, x1 = 0.f;
        float y0 = 0.f, y1 = 0.f;
        int j = jb + q;
        for (; j + 2 < je; j += 4) {        // this lane: j and j+2
            float4 ra = rec[csr_src[j]];
            float4 rb = rec[csr_src[j + 2]];
            float pa = exp2f(leaky(ra.x + adn));
            float pb = exp2f(leaky(rb.x + adn));
            l0 += pa; x0 += pa * ra.y; y0 += pa * ra.z;
            l1 += pb; x1 += pb * rb.y; y1 += pb * rb.z;
        }
        if (j < je) {
            float4 ra = rec[csr_src[j]];
            float pa = exp2f(leaky(ra.x + adn));
            l0 += pa; x0 += pa * ra.y; y0 += pa * ra.z;
        }
        float l = l0 + l1, xx = x0 + x1, yy = y0 + y1;
        l += __shfl_xor(l, 1, 64);
        xx += __shfl_xor(xx, 1, 64);
        yy += __shfl_xor(yy, 1, 64);
        if (q == 0) {
            float inv = 1.f / (l + 1e-16f);
            int g = batch[n];
            atomicAdd(&ls[g * 2],     xx * inv);
            atomicAdd(&ls[g * 2 + 1], yy * inv);
            atomicAdd(&ls[128 + g],   1.f);
        }
    }
    __syncthreads();
    if (tid < 192) atomicAdd(&pooled[tid], ls[tid]);
}

// ---------- finalize: mean, +b2, log_softmax ----------
__global__ __launch_bounds__(64) void final_kernel(
        const float* __restrict__ pooled, const float* __restrict__ b2,
        float* __restrict__ out) {
    int g = threadIdx.x;
    if (g >= 64) return;
    float c = pooled[128 + g];
    float denom = c > 1.f ? c : 1.f;
    float p0 = pooled[g * 2] / denom + b2[0];
    float p1 = pooled[g * 2 + 1] / denom + b2[1];
    float m = fmaxf(p0, p1);
    float lse = m + logf(expf(p0 - m) + expf(p1 - m));
    out[g * 2] = p0 - lse;
    out[g * 2 + 1] = p1 - lse;
}

extern "C" void kernel_launch(void* const* d_in, const int* in_sizes, int n_in,
                              void* d_out, int out_size, void* d_ws, size_t ws_size,
                              hipStream_t stream) {
    const float* x   = (const float*)d_in[0];
    const int*   ei  = (const int*)d_in[1];     // [2,E] int32
    const int*   bat = (const int*)d_in[2];     // [N]
    const float* W1  = (const float*)d_in[3];
    const float* as1 = (const float*)d_in[4];
    const float* ad1 = (const float*)d_in[5];
    const float* b1  = (const float*)d_in[6];
    const float* W2  = (const float*)d_in[7];
    const float* as2 = (const float*)d_in[8];
    const float* ad2 = (const float*)d_in[9];
    const float* b2  = (const float*)d_in[10];
    float* out = (float*)d_out;

    float* ws = (float*)d_ws;
    // workspace layout (element offsets; 16B-aligned blocks)
    const long off_nrec   = 0;                               // (NN+1)*128B
    const long off_wt     = off_nrec + (long)(NN + 1) * 32;  // 8192 halves
    const long off_rec    = off_wt + 4096;                   // NN*4 (float4)
    const long off_rowptr = off_rec + (long)NN * 4;          // N (int)
    const long off_rowend = off_rowptr + NN;                 // N (int)
    const long off_gpay   = off_rowend + NN;                 // NBUCK*SLAB (uint)
    const long off_csr    = off_gpay + (long)NBUCK * SLAB;   // NBUCK*SLAB (int)
    const long off_zero   = off_csr + (long)NBUCK * SLAB;    // ---- zeroed ----
    const long off_bcur   = off_zero;                        // NBUCK*PAD (int)
    const long off_pool   = off_bcur + (long)NBUCK * PAD;    // 192
    const long zero_elems = off_pool + 192 - off_zero;

    hipMemsetAsync(ws + off_zero, 0, zero_elems * sizeof(float), stream);

    bucket_fill<<<NCH2, 1024, 0, stream>>>(
        ei, (int*)(ws + off_bcur), (unsigned*)(ws + off_gpay),
        W1, (f16*)(ws + off_wt), (unsigned char*)(ws + off_nrec));

    gemm_csr_fused<<<NBUCK + GEMM_BLOCKS, 256, 0, stream>>>(
        (const unsigned*)(ws + off_gpay), (const int*)(ws + off_bcur),
        (int*)(ws + off_rowptr), (int*)(ws + off_rowend),
        (int*)(ws + off_csr),
        x, (const f16*)(ws + off_wt), as1, ad1,
        (unsigned char*)(ws + off_nrec));

    conv1_fused_kernel<<<NN / 16, 256, 0, stream>>>(
        (const int*)(ws + off_rowptr), (const int*)(ws + off_rowend),
        (const int*)(ws + off_csr), (const unsigned char*)(ws + off_nrec),
        b1, W2, as2, ad2, (float4*)(ws + off_rec));

    conv2_pool_kernel<<<(NN + 127) / 128, 256, 0, stream>>>(
        (const int*)(ws + off_rowptr), (const int*)(ws + off_rowend),
        (const int*)(ws + off_csr), (const float4*)(ws + off_rec),
        bat, ws + off_pool);

    final_kernel<<<1, 64, 0, stream>>>(ws + off_pool, b2, out);
}

// Round 10
// 223.366 us; speedup vs baseline: 1.0782x; 1.0478x over previous
//
#include <hip/hip_runtime.h>
#include <hip/hip_bf16.h>
#include <hip/hip_fp16.h>
#include <math.h>

// Problem constants
#define NN 100000
#define EE 1600000
#define ET 1700000            // E + N self-loops
#define NEG_SLOPE 0.2f
#define XS_STRIDE 136         // 128 + 8 halves: kills LDS bank conflicts
#define L2E 1.44269504088896f

// bucket-sort CSR build (fixed slabs; no count/scan passes)
#define BKB 7                 // log2(dsts per bucket)
#define BKSZ 128
#define NBUCK 782             // ceil(NN / BKSZ)
#define SLAB 4096             // slots per bucket (mean ~2174 +pad ~2622, 31 sigma)
#define PAD 32                // ints per counter (one 128B line each)
#define EPT2 4                // edges per thread (1024-thread blocks)
#define CHUNK2 (1024 * EPT2)  // 4096 edges per block
#define NCH2 ((ET + CHUNK2 - 1) / CHUNK2)   // 416

typedef _Float16 f16;
typedef f16 f16x4 __attribute__((ext_vector_type(4)));
typedef f16 f16x8 __attribute__((ext_vector_type(8)));
typedef float f32x4 __attribute__((ext_vector_type(4)));
typedef float f32x2 __attribute__((ext_vector_type(2)));

__device__ __forceinline__ float leaky(float v) {
    // slope in (0,1): leaky == max(v, slope*v) — 2 VALU, no branch
    return fmaxf(v, NEG_SLOPE * v);
}
__device__ __forceinline__ unsigned char enc_fp8(float v) {
    int pk = __builtin_amdgcn_cvt_pk_fp8_f32(v, 0.f, 0, false);
    return (unsigned char)(pk & 0xff);
}

// pair-fold: lanes with sb=0 keep X-sums, sb=1 keep Y-sums across offset off
__device__ __forceinline__ void fold8(float (&dst)[8], const float (&X)[8],
                                      const float (&Y)[8], int sb, int off) {
#pragma unroll
    for (int i = 0; i < 8; ++i) {
        float m = sb ? Y[i] : X[i];
        float o = sb ? X[i] : Y[i];
        dst[i] = m + __shfl_xor(o, off, 64);
    }
}

// node record: 128B per node = 8 heads x 16B chunk
//   chunk layout: [0:8) fp8 features (8 ch), [8:10) alpha_src half (pre *log2e),
//                 [10:12) pad, [12:16) alpha_dst float (pre *log2e)
// dummy record at node NN: fp8 = 0, alpha_src = -inf -> p = exp2(-inf) = 0

// ---------- B1: bucket fill (1024 thr, 4 edges/thr: 4x occupancy) --------
// R9-measured win vs 256-thr (47-50 -> <42 us). Merged convert_w + dummy.
__global__ __launch_bounds__(1024) void bucket_fill(
        const int* __restrict__ ei, int* __restrict__ bcur,
        unsigned* __restrict__ gpay, const float* __restrict__ W1,
        f16* __restrict__ wt, unsigned char* __restrict__ nrec) {
    const int tid = threadIdx.x;
    // merged convert_w: W1 fp32 [128][64] -> wt fp16 [64][128] (transposed)
    if (blockIdx.x < 8) {
        int i = blockIdx.x * 1024 + tid;     // 8*1024 == 128*64
        int n = i >> 7, k = i & 127;
        wt[n * 128 + k] = (f16)W1[k * 64 + n];
    }
    if (blockIdx.x == 8 && tid < 8) {
        uint4* dr = (uint4*)(nrec + (size_t)NN * 128);
        dr[tid] = make_uint4(0u, 0u, 0xFC00u, 0u);  // as1h = -inf
    }
    __shared__ int lcnt[NBUCK];
    __shared__ int gbase[NBUCK];
    for (int i = tid; i < NBUCK; i += 1024) lcnt[i] = 0;
    __syncthreads();
    const int base = blockIdx.x * CHUNK2 + tid;
    unsigned pay[EPT2];
    int bk[EPT2], pos[EPT2];
#pragma unroll
    for (int k = 0; k < EPT2; ++k) {
        int e = base + k * 1024;
        if (e < ET) {
            int s, d;
            if (e < EE) {
                s = __builtin_nontemporal_load(ei + e);
                d = __builtin_nontemporal_load(ei + EE + e);
            } else { s = d = e - EE; }
            int b = d >> BKB;
            bk[k] = b;
            pay[k] = ((unsigned)(d & (BKSZ - 1)) << 17) | (unsigned)s;
            pos[k] = atomicAdd(&lcnt[b], 1);
        } else bk[k] = -1;
    }
    __syncthreads();
    for (int i = tid; i < NBUCK; i += 1024)
        gbase[i] = lcnt[i] ? (i * SLAB + atomicAdd(&bcur[i * PAD], lcnt[i])) : 0;
    __syncthreads();
#pragma unroll
    for (int k = 0; k < EPT2; ++k)
        if (bk[k] >= 0) gpay[gbase[bk[k]] + pos[k]] = pay[k];
}

// ---------- GEMM1 via MFMA; fused alpha epilogue -> packed node records ---
// Standalone (un-fused from R8/R9): shared-kernel regalloc had capped VGPR
// at 40 and crippled the bf[4][4] weight-fragment registers.
__global__ __launch_bounds__(256) void gemm1_mfma(
        const float* __restrict__ x, const f16* __restrict__ wt,
        const float* __restrict__ att_s, const float* __restrict__ att_d,
        unsigned char* __restrict__ nrec) {
    __shared__ f16 xs[64 * XS_STRIDE];
    const int tid = threadIdx.x;
    const int node0 = blockIdx.x * 64;
    for (int i = tid; i < 64 * 32; i += 256) {
        int r = i >> 5, cp = i & 31;
        int n = node0 + r;
        float4 v = (n < NN) ? ((const float4*)x)[(long)n * 32 + cp]
                            : make_float4(0.f, 0.f, 0.f, 0.f);
        f16x4 h = {(f16)v.x, (f16)v.y, (f16)v.z, (f16)v.w};
        *(f16x4*)(xs + r * XS_STRIDE + 4 * cp) = h;
    }
    __syncthreads();
    const int wv = tid >> 6;
    const int lane = tid & 63;
    const int n16 = lane & 15;
    const int quad = lane >> 4;
    f16x8 bf[4][4];
#pragma unroll
    for (int t = 0; t < 4; ++t)
#pragma unroll
        for (int kk = 0; kk < 4; ++kk)
            bf[t][kk] = *(const f16x8*)(wt + ((t * 16 + n16) * 128 + kk * 32 + quad * 8));
    f32x4 acc[4] = {{0,0,0,0},{0,0,0,0},{0,0,0,0},{0,0,0,0}};
#pragma unroll
    for (int kk = 0; kk < 4; ++kk) {
        f16x8 af = *(const f16x8*)(xs + ((wv * 16 + n16) * XS_STRIDE + kk * 32 + quad * 8));
#pragma unroll
        for (int t = 0; t < 4; ++t)
            acc[t] = __builtin_amdgcn_mfma_f32_16x16x32_f16(af, bf[t][kk], acc[t], 0, 0, 0);
    }
    float ats[4], atd[4];
#pragma unroll
    for (int t = 0; t < 4; ++t) {
        ats[t] = att_s[t * 16 + n16];
        atd[t] = att_d[t * 16 + n16];
    }
    const int head = (n16 >> 3);            // + t*2
    const int chpos = n16 & 7;
#pragma unroll
    for (int t = 0; t < 4; ++t)
#pragma unroll
        for (int r = 0; r < 4; ++r) {
            int m = node0 + wv * 16 + quad * 4 + r;
            bool ok = (m < NN);
            if (ok)
                nrec[(size_t)m * 128 + (t * 2 + head) * 16 + chpos] =
                    enc_fp8(acc[t][r]);
            float vs = acc[t][r] * ats[t];
            float vd = acc[t][r] * atd[t];
            vs += __shfl_xor(vs, 1, 64); vd += __shfl_xor(vd, 1, 64);
            vs += __shfl_xor(vs, 2, 64); vd += __shfl_xor(vd, 2, 64);
            vs += __shfl_xor(vs, 4, 64); vd += __shfl_xor(vd, 4, 64);
            if (ok && chpos == 0) {
                unsigned char* nb = nrec + (size_t)m * 128 + (t * 2 + head) * 16;
                *(__half*)(nb + 8)  = __float2half_rn(vs * L2E);
                *(float*)(nb + 12) = vd * L2E;
            }
        }
}

// ---------- B2: fine CSR within each bucket slab; rows padded to x8 ------
__global__ __launch_bounds__(256) void fine_csr(
        const unsigned* __restrict__ gpay, const int* __restrict__ bcur,
        int* __restrict__ rowptr, int* __restrict__ rowend,
        int* __restrict__ csr_src) {
    __shared__ int cnt[BKSZ];     // 128: hist -> cursors
    __shared__ int ts[256];
    const int b = blockIdx.x;
    const int tid = threadIdx.x;
    const int off = b * SLAB;
    int blen = bcur[b * PAD];
    if (blen > SLAB) blen = SLAB;
    const int d0 = b << BKB;
    if (tid < BKSZ) cnt[tid] = 0;
    __syncthreads();
    for (int i = tid; i < blen; i += 256)
        atomicAdd(&cnt[gpay[off + i] >> 17], 1);
    __syncthreads();
    int v = (tid < BKSZ) ? cnt[tid] : 0;
    int vp = (v + 7) & ~7;        // padded row length (multiple of 8)
    ts[tid] = vp;
    __syncthreads();
    for (int o = 1; o < 256; o <<= 1) {
        int u = (tid >= o) ? ts[tid - o] : 0;
        __syncthreads();
        ts[tid] += u;
        __syncthreads();
    }
    int excl = ts[tid] - vp;
    if (excl + vp > SLAB) vp = v;  // pathological-overflow guard (>30 sigma)
    if (tid < BKSZ) cnt[tid] = excl;  // cursor = exclusive padded offset
    int d = d0 + tid;
    if (tid < BKSZ && d < NN) {
        rowptr[d] = off + excl;
        rowend[d] = off + excl + v;   // TRUE end (conv2 uses this)
    }
    // fill this row's pad slots with the dummy node (no-op for tid>=BKSZ)
    for (int i = v; i < vp; ++i) csr_src[off + excl + i] = NN;
    __syncthreads();
    for (int i = tid; i < blen; i += 256) {
        unsigned pay = gpay[off + i];
        int pos = atomicAdd(&cnt[pay >> 17], 1);
        csr_src[off + pos] = (int)(pay & 0x1FFFFu);
    }
}

// ---------- conv1 fused: 4 nodes per wave, unified masked loop -----------
__global__ __launch_bounds__(256) void conv1_fused_kernel(
        const int* __restrict__ rowptr, const int* __restrict__ rowend,
        const int* __restrict__ csr_src, const unsigned char* __restrict__ nrec,
        const float* __restrict__ b1, const float* __restrict__ W2,
        const float* __restrict__ as2, const float* __restrict__ ad2,
        float4* __restrict__ rec) {
    const int tid = threadIdx.x;
    const int wv = tid >> 6;
    const int c = tid & 63;
    const int slot = c >> 3;      // edge slot within an 8-edge group
    const int hd = c & 7;         // head; lane owns channels hd*8..hd*8+7
    const int sb0 = slot & 1, sb1 = (slot >> 1) & 1, sb2 = (slot >> 2) & 1;
    int n0 = __builtin_amdgcn_readfirstlane((blockIdx.x * 4 + wv) * 4);
    // nodes n0..n0+3; grid*4*4 == NN exactly
    const float adA = *(const float*)(nrec + ((size_t)(n0 + 0) << 7) + (hd << 4) + 12);
    const float adB = *(const float*)(nrec + ((size_t)(n0 + 1) << 7) + (hd << 4) + 12);
    const float adC = *(const float*)(nrec + ((size_t)(n0 + 2) << 7) + (hd << 4) + 12);
    const float adD = *(const float*)(nrec + ((size_t)(n0 + 3) << 7) + (hd << 4) + 12);
    int jA = rowptr[n0 + 0], eA = jA + ((rowend[n0 + 0] - jA + 7) & ~7);
    int jB = rowptr[n0 + 1], eB = jB + ((rowend[n0 + 1] - jB + 7) & ~7);
    int jC = rowptr[n0 + 2], eC = jC + ((rowend[n0 + 2] - jC + 7) & ~7);
    int jD = rowptr[n0 + 3], eD = jD + ((rowend[n0 + 3] - jD + 7) & ~7);
    float accA[8] = {0,0,0,0,0,0,0,0}, accB[8] = {0,0,0,0,0,0,0,0};
    float accC[8] = {0,0,0,0,0,0,0,0}, accD[8] = {0,0,0,0,0,0,0,0};
    float lA = 0.f, lB = 0.f, lC = 0.f, lD = 0.f;

#define STEP(j, e, ad, l, acc)                                               \
    {                                                                        \
        int jj = (j) < (e) - 8 ? (j) : (e) - 8;   /* clamp: rows >= 8 */     \
        int src = csr_src[jj + slot];                                        \
        uint4 v = *(const uint4*)(nrec + (((size_t)src << 7) | (hd << 4)));  \
        unsigned short ush = (unsigned short)v.z;                            \
        float as = __half2float(*(const __half*)&ush);                       \
        float p = exp2f(leaky(as + (ad)));                                   \
        p = ((j) < (e)) ? p : 0.f;                                           \
        f32x2 f01 = __builtin_amdgcn_cvt_pk_f32_fp8((int)v.x, 0);            \
        f32x2 f23 = __builtin_amdgcn_cvt_pk_f32_fp8((int)v.x, 1);            \
        f32x2 f45 = __builtin_amdgcn_cvt_pk_f32_fp8((int)v.y, 0);            \
        f32x2 f67 = __builtin_amdgcn_cvt_pk_f32_fp8((int)v.y, 1);            \
        (l) += p;                                                            \
        acc[0] += p * f01.x; acc[1] += p * f01.y;                            \
        acc[2] += p * f23.x; acc[3] += p * f23.y;                            \
        acc[4] += p * f45.x; acc[5] += p * f45.y;                            \
        acc[6] += p * f67.x; acc[7] += p * f67.y;                            \
        (j) += 8;                                                            \
    }

    while (jA < eA || jB < eB || jC < eC || jD < eD) {
        STEP(jA, eA, adA, lA, accA);
        STEP(jB, eB, adB, lB, accB);
        STEP(jC, eC, adC, lC, accC);
        STEP(jD, eD, adD, lD, accD);
    }
#undef STEP

    // ---- pair-fold butterfly ----
    float P[8], Q[8];
    fold8(P, accA, accB, sb0, 8);
    fold8(Q, accC, accD, sb0, 8);
    float lP, lQ, lm, lo;
    lm = sb0 ? lB : lA; lo = sb0 ? lA : lB;
    lP = lm + __shfl_xor(lo, 8, 64);
    lm = sb0 ? lD : lC; lo = sb0 ? lC : lD;
    lQ = lm + __shfl_xor(lo, 8, 64);
    float R[8];
    fold8(R, P, Q, sb1, 16);
    lm = sb1 ? lQ : lP; lo = sb1 ? lP : lQ;
    float l = lm + __shfl_xor(lo, 16, 64);
    float S[4];
#pragma unroll
    for (int i = 0; i < 4; ++i) {
        float m = sb2 ? R[i + 4] : R[i];
        float o = sb2 ? R[i] : R[i + 4];
        S[i] = m + __shfl_xor(o, 32, 64);
    }
    l += __shfl_xor(l, 32, 64);
    const int cb = (hd << 3) + sb2 * 4;
    float inv = 1.f / (l + 1e-16f);
    float4 bb = *(const float4*)(b1 + cb);
    float4 w01 = *(const float4*)(W2 + cb * 2);
    float4 w23 = *(const float4*)(W2 + cb * 2 + 4);
    float v0 = fmaxf(S[0] * inv + bb.x, 0.f);
    float v1 = fmaxf(S[1] * inv + bb.y, 0.f);
    float v2 = fmaxf(S[2] * inv + bb.z, 0.f);
    float v3 = fmaxf(S[3] * inv + bb.w, 0.f);
    float r0 = v0 * w01.x + v1 * w01.z + v2 * w23.x + v3 * w23.z;
    float r1 = v0 * w01.y + v1 * w01.w + v2 * w23.y + v3 * w23.w;
    r0 += __shfl_xor(r0, 1, 64);  r1 += __shfl_xor(r1, 1, 64);
    r0 += __shfl_xor(r0, 2, 64);  r1 += __shfl_xor(r1, 2, 64);
    r0 += __shfl_xor(r0, 4, 64);  r1 += __shfl_xor(r1, 4, 64);
    r0 += __shfl_xor(r0, 32, 64); r1 += __shfl_xor(r1, 32, 64);
    if (hd == 0 && sb2 == 0) {
        int n = n0 + sb1 * 2 + sb0;
        rec[n] = make_float4((r0 * as2[0] + r1 * as2[1]) * L2E, r0, r1,
                             (r0 * ad2[0] + r1 * ad2[1]) * L2E);
    }
}

// ---------- conv2 fused with mean-pool (LDS partials, prefetched) --------
__global__ __launch_bounds__(256) void conv2_pool_kernel(
        const int* __restrict__ rowptr, const int* __restrict__ rowend,
        const int* __restrict__ csr_src, const float4* __restrict__ rec,
        const int* __restrict__ batch,
        float* __restrict__ pooled /*128 sums + 64 counts*/) {
    __shared__ float ls[192];
    int tid = threadIdx.x;
    if (tid < 192) ls[tid] = 0.f;
    __syncthreads();
    int n = blockIdx.x * 256 + tid;
    if (n < NN) {
        float adn = rec[n].w;
        int jb = rowptr[n], je = rowend[n];
        float l0 = 0.f, l1 = 0.f, l2 = 0.f, l3 = 0.f;
        float x0 = 0.f, x1 = 0.f, x2 = 0.f, x3 = 0.f;
        float y0 = 0.f, y1 = 0.f, y2 = 0.f, y3 = 0.f;
        int j = jb;
        // prefetch 4 indices (rows are padded >= 8 slots: reads are real data)
        int i0 = csr_src[j], i1 = csr_src[j + 1];
        int i2 = csr_src[j + 2], i3 = csr_src[j + 3];
        for (; j + 3 < je; ) {
            float4 ra = rec[i0];
            float4 rb = rec[i1];
            float4 rc = rec[i2];
            float4 rd = rec[i3];
            j += 4;
            // prefetch next group's indices (dereferenced only if loop
            // continues, i.e. they were in-row)
            i0 = csr_src[j] & 0x1FFFF;     i1 = csr_src[j + 1] & 0x1FFFF;
            i2 = csr_src[j + 2] & 0x1FFFF; i3 = csr_src[j + 3] & 0x1FFFF;
            float pa = exp2f(leaky(ra.x + adn));
            float pb = exp2f(leaky(rb.x + adn));
            float pc = exp2f(leaky(rc.x + adn));
            float pd = exp2f(leaky(rd.x + adn));
            l0 += pa; x0 += pa * ra.y; y0 += pa * ra.z;
            l1 += pb; x1 += pb * rb.y; y1 += pb * rb.z;
            l2 += pc; x2 += pc * rc.y; y2 += pc * rc.z;
            l3 += pd; x3 += pd * rd.y; y3 += pd * rd.z;
        }
        for (; j < je; ++j) {
            float4 ra = rec[csr_src[j]];
            float pa = exp2f(leaky(ra.x + adn));
            l0 += pa; x0 += pa * ra.y; y0 += pa * ra.z;
        }
        float l = (l0 + l1) + (l2 + l3);
        float xx = (x0 + x1) + (x2 + x3);
        float yy = (y0 + y1) + (y2 + y3);
        float inv = 1.f / (l + 1e-16f);
        int g = batch[n];
        atomicAdd(&ls[g * 2],     xx * inv);
        atomicAdd(&ls[g * 2 + 1], yy * inv);
        atomicAdd(&ls[128 + g],   1.f);
    }
    __syncthreads();
    if (tid < 192) atomicAdd(&pooled[tid], ls[tid]);
}

// ---------- finalize: mean, +b2, log_softmax ----------
__global__ __launch_bounds__(64) void final_kernel(
        const float* __restrict__ pooled, const float* __restrict__ b2,
        float* __restrict__ out) {
    int g = threadIdx.x;
    if (g >= 64) return;
    float c = pooled[128 + g];
    float denom = c > 1.f ? c : 1.f;
    float p0 = pooled[g * 2] / denom + b2[0];
    float p1 = pooled[g * 2 + 1] / denom + b2[1];
    float m = fmaxf(p0, p1);
    float lse = m + logf(expf(p0 - m) + expf(p1 - m));
    out[g * 2] = p0 - lse;
    out[g * 2 + 1] = p1 - lse;
}

extern "C" void kernel_launch(void* const* d_in, const int* in_sizes, int n_in,
                              void* d_out, int out_size, void* d_ws, size_t ws_size,
                              hipStream_t stream) {
    const float* x   = (const float*)d_in[0];
    const int*   ei  = (const int*)d_in[1];     // [2,E] int32
    const int*   bat = (const int*)d_in[2];     // [N]
    const float* W1  = (const float*)d_in[3];
    const float* as1 = (const float*)d_in[4];
    const float* ad1 = (const float*)d_in[5];
    const float* b1  = (const float*)d_in[6];
    const float* W2  = (const float*)d_in[7];
    const float* as2 = (const float*)d_in[8];
    const float* ad2 = (const float*)d_in[9];
    const float* b2  = (const float*)d_in[10];
    float* out = (float*)d_out;

    float* ws = (float*)d_ws;
    // workspace layout (element offsets; 16B-aligned blocks)
    const long off_nrec   = 0;                               // (NN+1)*128B
    const long off_wt     = off_nrec + (long)(NN + 1) * 32;  // 8192 halves
    const long off_rec    = off_wt + 4096;                   // NN*4 (float4)
    const long off_rowptr = off_rec + (long)NN * 4;          // N (int)
    const long off_rowend = off_rowptr + NN;                 // N (int)
    const long off_gpay   = off_rowend + NN;                 // NBUCK*SLAB (uint)
    const long off_csr    = off_gpay + (long)NBUCK * SLAB;   // NBUCK*SLAB (int)
    const long off_zero   = off_csr + (long)NBUCK * SLAB;    // ---- zeroed ----
    const long off_bcur   = off_zero;                        // NBUCK*PAD (int)
    const long off_pool   = off_bcur + (long)NBUCK * PAD;    // 192
    const long zero_elems = off_pool + 192 - off_zero;

    hipMemsetAsync(ws + off_zero, 0, zero_elems * sizeof(float), stream);

    bucket_fill<<<NCH2, 1024, 0, stream>>>(
        ei, (int*)(ws + off_bcur), (unsigned*)(ws + off_gpay),
        W1, (f16*)(ws + off_wt), (unsigned char*)(ws + off_nrec));

    gemm1_mfma<<<(NN + 63) / 64, 256, 0, stream>>>(
        x, (const f16*)(ws + off_wt), as1, ad1,
        (unsigned char*)(ws + off_nrec));

    fine_csr<<<NBUCK, 256, 0, stream>>>(
        (const unsigned*)(ws + off_gpay), (const int*)(ws + off_bcur),
        (int*)(ws + off_rowptr), (int*)(ws + off_rowend),
        (int*)(ws + off_csr));

    conv1_fused_kernel<<<NN / 16, 256, 0, stream>>>(
        (const int*)(ws + off_rowptr), (const int*)(ws + off_rowend),
        (const int*)(ws + off_csr), (const unsigned char*)(ws + off_nrec),
        b1, W2, as2, ad2, (float4*)(ws + off_rec));

    conv2_pool_kernel<<<(NN + 255) / 256, 256, 0, stream>>>(
        (const int*)(ws + off_rowptr), (const int*)(ws + off_rowend),
        (const int*)(ws + off_csr), (const float4*)(ws + off_rec),
        bat, ws + off_pool);

    final_kernel<<<1, 64, 0, stream>>>(ws + off_pool, b2, out);
}